// Round 1
// baseline (1763.722 us; speedup 1.0000x reference)
//
#include <hip/hip_runtime.h>
#include <hip/hip_bf16.h>
#include <cstdint>

#define HID 256
#define NGRAPH 16
#define NEG_SLOPE 0.01f

#define BM 128
#define BN 64
#define BK 16

__device__ __forceinline__ float leaky(float x) { return x >= 0.f ? x : NEG_SLOPE * x; }

// ---------------- CSR build ----------------
__global__ __launch_bounds__(256) void k_zero_i32(int* p, int n) {
  int i = blockIdx.x * blockDim.x + threadIdx.x;
  if (i < n) p[i] = 0;
}

__global__ __launch_bounds__(256) void k_hist(const int* __restrict__ key, int* __restrict__ cnt, int ne) {
  int e = blockIdx.x * blockDim.x + threadIdx.x;
  if (e < ne) atomicAdd(&cnt[key[e]], 1);
}

__global__ __launch_bounds__(1024) void k_scan(const int* __restrict__ cnt, int* __restrict__ rowptr,
                                               int* __restrict__ cursor, int n) {
  __shared__ int sd[1024];
  int tid = threadIdx.x;
  int CH = n / 1024 + 1;
  int base = tid * CH;
  int s = 0;
  for (int i = 0; i < CH; ++i) { int idx = base + i; if (idx < n) s += cnt[idx]; }
  sd[tid] = s;
  __syncthreads();
  for (int off = 1; off < 1024; off <<= 1) {
    int v = (tid >= off) ? sd[tid - off] : 0;
    __syncthreads();
    sd[tid] += v;
    __syncthreads();
  }
  int run = (tid == 0) ? 0 : sd[tid - 1];
  for (int i = 0; i < CH; ++i) {
    int idx = base + i;
    if (idx <= n) {
      rowptr[idx] = run;
      if (idx < n) { cursor[idx] = run; run += cnt[idx]; }
    }
  }
}

__global__ __launch_bounds__(64) void k_gscan(const int* __restrict__ gcnt, int* __restrict__ gstart) {
  if (threadIdx.x == 0) {
    int run = 0;
    for (int g = 0; g < NGRAPH; ++g) { gstart[g] = run; run += gcnt[g]; }
    gstart[NGRAPH] = run;
  }
}

__global__ __launch_bounds__(256) void k_scatter(const int* __restrict__ src, const int* __restrict__ dst,
                                                 int* __restrict__ cursor, int* __restrict__ col, int ne) {
  int e = blockIdx.x * blockDim.x + threadIdx.x;
  if (e < ne) {
    int d = dst[e];
    int pos = atomicAdd(&cursor[d], 1);
    col[pos] = src[e];
  }
}

// ---------------- neighbor aggregation: S[i] = h[i] + sum_{j->i} h[j]; degf[i]=indeg+1 ----------------
__global__ __launch_bounds__(256) void k_aggregate(const float* __restrict__ h, const int* __restrict__ rowptr,
                                                   const int* __restrict__ col, float* __restrict__ S,
                                                   float* __restrict__ degf, int n) {
  int node = blockIdx.x * 4 + (threadIdx.x >> 6);
  if (node >= n) return;
  int lane = threadIdx.x & 63;
  const float4* h4 = (const float4*)h;
  size_t base = (size_t)node * 64 + lane;
  float4 acc = h4[base];  // self-loop contribution
  int beg = rowptr[node], end = rowptr[node + 1];
  for (int p = beg; p < end; ++p) {
    int j = col[p];
    float4 v = h4[(size_t)j * 64 + lane];
    acc.x += v.x; acc.y += v.y; acc.z += v.z; acc.w += v.w;
  }
  ((float4*)S)[base] = acc;
  if (lane == 0) degf[node] = (float)(end - beg + 1);
}

// ---------------- tiled fp32 GEMM: C = act( [rs.*A0]@W0 (+ A1@W1) + rs.*bias ) ----------------
// A: [M][K] row-major, W: [K][N] row-major. rowscale (optional) scales A0 rows and the bias.
__global__ __launch_bounds__(256) void k_gemm(
    const float* __restrict__ A0, const float* __restrict__ W0,
    const float* __restrict__ A1, const float* __restrict__ W1,
    const float* __restrict__ bias, const float* __restrict__ rowscale,
    float* __restrict__ C, int M, int N, int K, int act)
{
  __shared__ float As[BK][BM + 4];  // +4 pad: keeps 16B alignment, 2-way conflicts only
  __shared__ float Bs[BK][BN + 4];
  int tid = threadIdx.x;
  int tx = tid & 15;        // 16 col-groups of 4
  int ty = tid >> 4;        // 16 row-groups of 8
  int m0 = blockIdx.x * BM;
  int n0 = blockIdx.y * BN;

  float c[8][4];
#pragma unroll
  for (int i = 0; i < 8; ++i)
#pragma unroll
    for (int j = 0; j < 4; ++j) c[i][j] = 0.f;

  int la_m = tid >> 2;            // 0..63 (and +64)
  int la_k = (tid & 3) << 2;      // 0,4,8,12
  int lb_k = tid >> 4;            // 0..15
  int lb_n = (tid & 15) << 2;     // 0..60

  int am1 = m0 + la_m;
  int am2 = am1 + 64;
  int bn = n0 + lb_n;
  bool bok = (bn + 4) <= N;

  int npass = (A1 != nullptr) ? 2 : 1;
  for (int p = 0; p < npass; ++p) {
    const float* __restrict__ A = p ? A1 : A0;
    const float* __restrict__ W = p ? W1 : W0;
    bool scale = (p == 0) && (rowscale != nullptr);
    float rs1 = 1.f, rs2 = 1.f;
    if (scale) {
      if (am1 < M) rs1 = rowscale[am1];
      if (am2 < M) rs2 = rowscale[am2];
    }
    for (int k0 = 0; k0 < K; k0 += BK) {
      float4 av1 = make_float4(0.f, 0.f, 0.f, 0.f), av2 = av1;
      if (am1 < M) av1 = *(const float4*)&A[(size_t)am1 * K + k0 + la_k];
      if (am2 < M) av2 = *(const float4*)&A[(size_t)am2 * K + k0 + la_k];
      if (scale) {
        av1.x *= rs1; av1.y *= rs1; av1.z *= rs1; av1.w *= rs1;
        av2.x *= rs2; av2.y *= rs2; av2.z *= rs2; av2.w *= rs2;
      }
      float4 bv = make_float4(0.f, 0.f, 0.f, 0.f);
      if (bok) bv = *(const float4*)&W[(size_t)(k0 + lb_k) * N + bn];
      __syncthreads();
      As[la_k + 0][la_m] = av1.x;
      As[la_k + 1][la_m] = av1.y;
      As[la_k + 2][la_m] = av1.z;
      As[la_k + 3][la_m] = av1.w;
      As[la_k + 0][la_m + 64] = av2.x;
      As[la_k + 1][la_m + 64] = av2.y;
      As[la_k + 2][la_m + 64] = av2.z;
      As[la_k + 3][la_m + 64] = av2.w;
      *(float4*)&Bs[lb_k][lb_n] = bv;
      __syncthreads();
#pragma unroll
      for (int k = 0; k < BK; ++k) {
        float4 a0 = *(const float4*)&As[k][ty * 8];
        float4 a1 = *(const float4*)&As[k][ty * 8 + 4];
        float4 b  = *(const float4*)&Bs[k][tx * 4];
        float a[8] = {a0.x, a0.y, a0.z, a0.w, a1.x, a1.y, a1.z, a1.w};
        float bb[4] = {b.x, b.y, b.z, b.w};
#pragma unroll
        for (int i = 0; i < 8; ++i)
#pragma unroll
          for (int j = 0; j < 4; ++j) c[i][j] += a[i] * bb[j];
      }
    }
  }

  int colbase = n0 + (tx << 2);
  if ((colbase + 4) > N) return;
  float4 bb = *(const float4*)&bias[colbase];
#pragma unroll
  for (int i = 0; i < 8; ++i) {
    int row = m0 + ty * 8 + i;
    if (row >= M) break;
    float rsv = (rowscale != nullptr) ? rowscale[row] : 1.f;
    float4 v;
    v.x = c[i][0] + bb.x * rsv;
    v.y = c[i][1] + bb.y * rsv;
    v.z = c[i][2] + bb.z * rsv;
    v.w = c[i][3] + bb.w * rsv;
    if (act) { v.x = leaky(v.x); v.y = leaky(v.y); v.z = leaky(v.z); v.w = leaky(v.w); }
    *(float4*)&C[(size_t)row * N + colbase] = v;
  }
}

// ---------------- pooling (batch sorted -> contiguous graph ranges) ----------------
__global__ __launch_bounds__(256) void k_pool1(const float* __restrict__ h, const int* __restrict__ gstart,
                                               const int* __restrict__ gcnt, float* __restrict__ psum,
                                               float* __restrict__ pmax) {
  int g = blockIdx.x >> 4;
  int cch = blockIdx.x & 15;
  int t = threadIdx.x;
  int len = gcnt[g];
  int s0 = gstart[g];
  int chunk = (len + 15) >> 4;
  int i0 = s0 + cch * chunk;
  int i1 = min(i0 + chunk, s0 + len);
  float s = 0.f;
  float m = -3.402823466e+38f;
  for (int i = i0; i < i1; ++i) {
    float v = h[(size_t)i * HID + t];
    s += v;
    m = fmaxf(m, v);
  }
  psum[(size_t)blockIdx.x * HID + t] = s;
  pmax[(size_t)blockIdx.x * HID + t] = m;
}

__global__ __launch_bounds__(256) void k_pool2(const float* __restrict__ psum, const float* __restrict__ pmax,
                                               const int* __restrict__ gcnt, float* __restrict__ pooled) {
  int g = blockIdx.x;
  int t = threadIdx.x;
  float s = 0.f, m = -3.402823466e+38f;
  for (int cch = 0; cch < 16; ++cch) {
    s += psum[(size_t)(g * 16 + cch) * HID + t];
    m = fmaxf(m, pmax[(size_t)(g * 16 + cch) * HID + t]);
  }
  float cf = (float)gcnt[g];
  pooled[g * 3 * HID + t] = s / fmaxf(cf, 1.f);  // mean
  pooled[g * 3 * HID + HID + t] = m;             // max
  pooled[g * 3 * HID + 2 * HID + t] = s;         // sum
}

// ---------------- launch ----------------
extern "C" void kernel_launch(void* const* d_in, const int* in_sizes, int n_in,
                              void* d_out, int out_size, void* d_ws, size_t ws_size,
                              hipStream_t stream) {
  const float* x        = (const float*)d_in[0];
  const int*   ei       = (const int*)d_in[1];
  const int*   batch    = (const int*)d_in[2];
  const float* enc_Win  = (const float*)d_in[3];
  const float* enc_bin  = (const float*)d_in[4];
  const float* enc_Wh   = (const float*)d_in[5];
  const float* enc_bh   = (const float*)d_in[6];
  const float* enc_Wout = (const float*)d_in[7];
  const float* enc_bout = (const float*)d_in[8];
  const float* edge_W   = (const float*)d_in[9];
  const float* edge_b   = (const float*)d_in[10];
  const float* proc_Win = (const float*)d_in[11];
  const float* proc_bin = (const float*)d_in[12];
  const float* proc_Wh  = (const float*)d_in[13];
  const float* proc_bh  = (const float*)d_in[14];
  const float* proc_Wout= (const float*)d_in[15];
  const float* proc_bout= (const float*)d_in[16];
  const float* dec_Win  = (const float*)d_in[17];
  const float* dec_bin  = (const float*)d_in[18];
  const float* dec_Wh   = (const float*)d_in[19];
  const float* dec_bh   = (const float*)d_in[20];
  const float* dec_Wout = (const float*)d_in[21];
  const float* dec_bout = (const float*)d_in[22];

  const int n  = in_sizes[0] / 128;  // 20000 nodes
  const int ne = in_sizes[1] / 2;    // 160000 edges
  const int H = HID;

  // workspace carve-up (~63 MB)
  float* B0     = (float*)d_ws;
  float* B1     = B0 + (size_t)n * H;
  float* S      = B1 + (size_t)n * H;
  float* degf   = S + (size_t)n * H;
  float* pooled = degf + n;
  float* psum   = pooled + NGRAPH * 3 * H;
  float* pmax   = psum + 256 * H;
  float* db0    = pmax + 256 * H;
  float* db1    = db0 + NGRAPH * H;
  int* cnt      = (int*)(db1 + NGRAPH * H);
  int* gcnt     = cnt + n;
  int* rowptr   = gcnt + NGRAPH;
  int* gstart   = rowptr + (n + 1);
  int* cursor   = gstart + (NGRAPH + 1);
  int* colv     = cursor + n;

  const int* srcI = ei;
  const int* dstI = ei + ne;

  dim3 blk(256);

  // CSR by destination + per-graph counts
  k_zero_i32<<<dim3((n + NGRAPH + 255) / 256), blk, 0, stream>>>(cnt, n + NGRAPH);
  k_hist<<<dim3((ne + 255) / 256), blk, 0, stream>>>(dstI, cnt, ne);
  k_hist<<<dim3((n + 255) / 256), blk, 0, stream>>>(batch, gcnt, n);
  k_scan<<<1, 1024, 0, stream>>>(cnt, rowptr, cursor, n);
  k_gscan<<<1, 64, 0, stream>>>(gcnt, gstart);
  k_scatter<<<dim3((ne + 255) / 256), blk, 0, stream>>>(srcI, dstI, cursor, colv, ne);

  dim3 g_full((n + BM - 1) / BM, (H + BN - 1) / BN);  // (157,4)

  // encoder MLP: leaky(x@Win+b), 2x leaky(@Wh+b), @Wout+b
  k_gemm<<<g_full, blk, 0, stream>>>(x,  enc_Win,        nullptr, nullptr, enc_bin,      nullptr, B0, n, H, 128, 1);
  k_gemm<<<g_full, blk, 0, stream>>>(B0, enc_Wh,         nullptr, nullptr, enc_bh,       nullptr, B1, n, H, H,   1);
  k_gemm<<<g_full, blk, 0, stream>>>(B1, enc_Wh + H * H, nullptr, nullptr, enc_bh + H,   nullptr, B0, n, H, H,   1);
  k_gemm<<<g_full, blk, 0, stream>>>(B0, enc_Wout,       nullptr, nullptr, enc_bout,     nullptr, B1, n, H, H,   0);

  // 4 message-passing rounds (shared weights); h lives in B1 at loop head
  for (int r = 0; r < 4; ++r) {
    k_aggregate<<<dim3((n + 3) / 4), blk, 0, stream>>>(B1, rowptr, colv, S, degf, n);
    // agg = deg.*(h@W1) + S@W2 + deg.*edge_b
    k_gemm<<<g_full, blk, 0, stream>>>(B1, edge_W, S, edge_W + H * H, edge_b, degf, B0, n, H, H, 0);
    // proc MLP
    k_gemm<<<g_full, blk, 0, stream>>>(B0, proc_Win,        nullptr, nullptr, proc_bin,    nullptr, S,  n, H, H, 1);
    k_gemm<<<g_full, blk, 0, stream>>>(S,  proc_Wh,         nullptr, nullptr, proc_bh,     nullptr, B0, n, H, H, 1);
    k_gemm<<<g_full, blk, 0, stream>>>(B0, proc_Wh + H * H, nullptr, nullptr, proc_bh + H, nullptr, S,  n, H, H, 1);
    k_gemm<<<g_full, blk, 0, stream>>>(S,  proc_Wout,       nullptr, nullptr, proc_bout,   nullptr, B1, n, H, H, 0);
  }

  // pooling: mean | max | sum  -> [16][768]
  k_pool1<<<dim3(NGRAPH * 16), blk, 0, stream>>>(B1, gstart, gcnt, psum, pmax);
  k_pool2<<<dim3(NGRAPH), blk, 0, stream>>>(psum, pmax, gcnt, pooled);

  // decoder MLP
  dim3 g_dec(1, (H + BN - 1) / BN);
  k_gemm<<<g_dec, blk, 0, stream>>>(pooled, dec_Win,        nullptr, nullptr, dec_bin,    nullptr, db0, NGRAPH, H, 3 * H, 1);
  k_gemm<<<g_dec, blk, 0, stream>>>(db0,    dec_Wh,         nullptr, nullptr, dec_bh,     nullptr, db1, NGRAPH, H, H, 1);
  k_gemm<<<g_dec, blk, 0, stream>>>(db1,    dec_Wh + H * H, nullptr, nullptr, dec_bh + H, nullptr, db0, NGRAPH, H, H, 1);
  k_gemm<<<dim3(1, 1), blk, 0, stream>>>(db0, dec_Wout,     nullptr, nullptr, dec_bout,   nullptr, (float*)d_out, NGRAPH, 32, H, 0);
}

// Round 2
// 730.151 us; speedup vs baseline: 2.4156x; 2.4156x over previous
//
#include <hip/hip_runtime.h>
#include <hip/hip_bf16.h>
#include <cstdint>

#define HID 256
#define NGRAPH 16
#define NEG_SLOPE 0.01f

typedef __bf16 bf16x8 __attribute__((ext_vector_type(8)));
typedef float f32x4 __attribute__((ext_vector_type(4)));

__device__ __forceinline__ float leaky(float x) { return x >= 0.f ? x : NEG_SLOPE * x; }

__device__ __forceinline__ ushort f2b(float f) {
  uint u = __float_as_uint(f);
  uint r = (u + 0x7fffu + ((u >> 16) & 1u)) >> 16;
  return (ushort)r;
}
__device__ __forceinline__ float b2f(ushort b) { return __uint_as_float((uint)b << 16); }

// ---------------- CSR build ----------------
__global__ __launch_bounds__(256) void k_zero_i32(int* p, int n) {
  int i = blockIdx.x * blockDim.x + threadIdx.x;
  if (i < n) p[i] = 0;
}

__global__ __launch_bounds__(256) void k_hist(const int* __restrict__ key, int* __restrict__ cnt, int ne) {
  int e = blockIdx.x * blockDim.x + threadIdx.x;
  if (e < ne) atomicAdd(&cnt[key[e]], 1);
}

__global__ __launch_bounds__(1024) void k_scan(const int* __restrict__ cnt, int* __restrict__ rowptr,
                                               int* __restrict__ cursor, int n) {
  __shared__ int sd[1024];
  int tid = threadIdx.x;
  int CH = n / 1024 + 1;
  int base = tid * CH;
  int s = 0;
  for (int i = 0; i < CH; ++i) { int idx = base + i; if (idx < n) s += cnt[idx]; }
  sd[tid] = s;
  __syncthreads();
  for (int off = 1; off < 1024; off <<= 1) {
    int v = (tid >= off) ? sd[tid - off] : 0;
    __syncthreads();
    sd[tid] += v;
    __syncthreads();
  }
  int run = (tid == 0) ? 0 : sd[tid - 1];
  for (int i = 0; i < CH; ++i) {
    int idx = base + i;
    if (idx <= n) {
      rowptr[idx] = run;
      if (idx < n) { cursor[idx] = run; run += cnt[idx]; }
    }
  }
}

// batch is sorted: per-graph bounds via binary search (replaces 16-bin atomic hist)
__global__ __launch_bounds__(64) void k_gbounds(const int* __restrict__ batch, int n,
                                                int* __restrict__ gstart, int* __restrict__ gcnt) {
  int t = threadIdx.x;
  if (t <= NGRAPH) {
    int lo = 0, hi = n;
    while (lo < hi) { int mid = (lo + hi) >> 1; if (batch[mid] < t) lo = mid + 1; else hi = mid; }
    gstart[t] = lo;
  }
  __syncthreads();
  if (t < NGRAPH) gcnt[t] = gstart[t + 1] - gstart[t];
}

__global__ __launch_bounds__(256) void k_scatter(const int* __restrict__ src, const int* __restrict__ dst,
                                                 int* __restrict__ cursor, int* __restrict__ col, int ne) {
  int e = blockIdx.x * blockDim.x + threadIdx.x;
  if (e < ne) {
    int d = dst[e];
    int pos = atomicAdd(&cursor[d], 1);
    col[pos] = src[e];
  }
}

// ---------------- conversions ----------------
__global__ __launch_bounds__(256) void k_f2b(const float* __restrict__ src, ushort* __restrict__ dst, int nElem) {
  int i = (blockIdx.x * 256 + threadIdx.x) * 4;
  if (i + 3 < nElem) {
    float4 v = *(const float4*)&src[i];
    ushort4 o;
    o.x = f2b(v.x); o.y = f2b(v.y); o.z = f2b(v.z); o.w = f2b(v.w);
    *(ushort4*)&dst[i] = o;
  } else {
    for (int j = i; j < nElem; ++j) dst[j] = f2b(src[j]);
  }
}

// transpose-convert: dst[n][k] = bf16(src[k][n]); src is [K][256]
__global__ __launch_bounds__(256) void k_wconv(const float* __restrict__ src, ushort* __restrict__ dst, int K) {
  __shared__ float t[32][33];
  int k0 = blockIdx.x * 32;
  int n0 = blockIdx.y * 32;
  int tx = threadIdx.x & 31;
  int ty = threadIdx.x >> 5;  // 0..7
#pragma unroll
  for (int r = 0; r < 4; ++r) t[ty + 8 * r][tx] = src[(size_t)(k0 + ty + 8 * r) * 256 + n0 + tx];
  __syncthreads();
#pragma unroll
  for (int r = 0; r < 4; ++r) dst[(size_t)(n0 + ty + 8 * r) * K + k0 + tx] = f2b(t[tx][ty + 8 * r]);
}

// ---------------- aggregation: S=self+neighbors (bf16), hd=deg*self (bf16), degf ----------------
__global__ __launch_bounds__(256) void k_aggregate(const ushort* __restrict__ h, const int* __restrict__ rowptr,
                                                   const int* __restrict__ col, ushort* __restrict__ S,
                                                   ushort* __restrict__ hd, float* __restrict__ degf, int n) {
  int node = blockIdx.x * 4 + (threadIdx.x >> 6);
  if (node >= n) return;
  int lane = threadIdx.x & 63;
  const ushort4* h4 = (const ushort4*)h;  // 4 bf16 per lane = 8B; 64 lanes = 512B row
  size_t base = (size_t)node * 64 + lane;
  ushort4 self = h4[base];
  float a0 = b2f(self.x), a1 = b2f(self.y), a2 = b2f(self.z), a3 = b2f(self.w);
  float s0 = a0, s1 = a1, s2 = a2, s3 = a3;
  int beg = rowptr[node], end = rowptr[node + 1];
  for (int p = beg; p < end; ++p) {
    int j = col[p];
    ushort4 v = h4[(size_t)j * 64 + lane];
    s0 += b2f(v.x); s1 += b2f(v.y); s2 += b2f(v.z); s3 += b2f(v.w);
  }
  float deg = (float)(end - beg + 1);
  ushort4 so; so.x = f2b(s0); so.y = f2b(s1); so.z = f2b(s2); so.w = f2b(s3);
  ((ushort4*)S)[base] = so;
  ushort4 ho; ho.x = f2b(deg * a0); ho.y = f2b(deg * a1); ho.z = f2b(deg * a2); ho.w = f2b(deg * a3);
  ((ushort4*)hd)[base] = ho;
  if (lane == 0) degf[node] = deg;
}

// ---------------- bf16 MFMA GEMM: C = act( A0@W0t^T (+ A1@W1t^T) + rs.*bias ), N=256 fixed ----------------
// A: [M][K] bf16 row-major. Wt: [256][ldw] bf16 (transposed weights, 8-contig k per frag read).
// tile 128x64, 4 waves (2x2), wave tile 64x32, BK=32, double-buffered LDS, reg-staged.
__global__ __launch_bounds__(256) void k_gemm_bf16(
    const ushort* __restrict__ A0, const ushort* __restrict__ W0t, int ldw0,
    const ushort* __restrict__ A1, const ushort* __restrict__ W1t, int ldw1,
    const float* __restrict__ bias, const float* __restrict__ rowscale,
    ushort* __restrict__ C, int M, int K, int act)
{
  __shared__ __align__(16) ushort lds[2][128 * 32 + 64 * 32];
  const int tid = threadIdx.x;
  const int lane = tid & 63;
  const int wid = tid >> 6;
  const int wm = wid >> 1;   // 0..1 : rows [wm*64, +64)
  const int wn = wid & 1;    // 0..1 : cols [wn*32, +32)
  const int rl = lane & 15;
  const int kg = lane >> 4;  // k-group 0..3 (8 contig bf16 each)
  const int m0 = blockIdx.x * 128;
  const int n0 = blockIdx.y * 64;
  const int KS = K >> 5;                 // k-steps per pass
  const int NT = (A1 ? 2 : 1) * KS;      // total steps

  f32x4 acc[4][2];
#pragma unroll
  for (int i = 0; i < 4; ++i)
#pragma unroll
    for (int j = 0; j < 2; ++j) acc[i][j] = (f32x4)(0.f);

  // staging slot precompute. A tile: 512 slots of 8 bf16; B tile: 256 slots.
  // slot s -> row=s>>2, sl=s&3; LDS content at (row,sl) = global k-group (sl ^ ((row>>1)&3))
  const int a_row0 = tid >> 2, a_sl0 = tid & 3;
  const int a_row1 = (tid + 256) >> 2, a_sl1 = tid & 3;  // same low bits
  const int a_kg0 = a_sl0 ^ ((a_row0 >> 1) & 3);
  const int a_kg1 = a_sl1 ^ ((a_row1 >> 1) & 3);
  const int b_row = tid >> 2, b_sl = tid & 3;
  const int b_kg = b_sl ^ ((b_row >> 1) & 3);
  int ga0 = m0 + a_row0; if (ga0 > M - 1) ga0 = M - 1;
  int ga1 = m0 + a_row1; if (ga1 > M - 1) ga1 = M - 1;

  bf16x8 ra0, ra1, rb;

#define LOAD_TILE(t)                                                                   \
  {                                                                                    \
    int p_ = (t) / KS;                                                                 \
    int k0_ = ((t) - p_ * KS) << 5;                                                    \
    const ushort* Ap_ = p_ ? A1 : A0;                                                  \
    const ushort* Wp_ = p_ ? W1t : W0t;                                                \
    int ldw_ = p_ ? ldw1 : ldw0;                                                       \
    ra0 = *(const bf16x8*)&Ap_[(size_t)ga0 * K + k0_ + a_kg0 * 8];                     \
    ra1 = *(const bf16x8*)&Ap_[(size_t)ga1 * K + k0_ + a_kg1 * 8];                     \
    rb  = *(const bf16x8*)&Wp_[(size_t)(n0 + b_row) * ldw_ + k0_ + b_kg * 8];          \
  }

#define STORE_TILE(b)                                                                  \
  {                                                                                    \
    ushort* dA_ = &lds[b][0];                                                          \
    ushort* dB_ = &lds[b][128 * 32];                                                   \
    *(bf16x8*)&dA_[(size_t)tid * 8] = ra0;                                             \
    *(bf16x8*)&dA_[(size_t)(tid + 256) * 8] = ra1;                                     \
    *(bf16x8*)&dB_[(size_t)tid * 8] = rb;                                              \
  }

  LOAD_TILE(0);
  STORE_TILE(0);

  for (int t = 0; t < NT; ++t) {
    if (t + 1 < NT) LOAD_TILE(t + 1);
    __syncthreads();
    const ushort* bA = &lds[t & 1][0];
    const ushort* bB = &lds[t & 1][128 * 32];
    bf16x8 af[4], bfr[2];
#pragma unroll
    for (int fm = 0; fm < 4; ++fm) {
      int r = wm * 64 + fm * 16 + rl;
      int sl = kg ^ ((r >> 1) & 3);
      af[fm] = *(const bf16x8*)&bA[r * 32 + sl * 8];
    }
#pragma unroll
    for (int fn = 0; fn < 2; ++fn) {
      int rn = wn * 32 + fn * 16 + rl;
      int sl = kg ^ ((rn >> 1) & 3);
      bfr[fn] = *(const bf16x8*)&bB[rn * 32 + sl * 8];
    }
#pragma unroll
    for (int fm = 0; fm < 4; ++fm)
#pragma unroll
      for (int fn = 0; fn < 2; ++fn)
        acc[fm][fn] = __builtin_amdgcn_mfma_f32_16x16x32_bf16(af[fm], bfr[fn], acc[fm][fn], 0, 0, 0);
    if (t + 1 < NT) STORE_TILE((t + 1) & 1);
  }

  // epilogue: C/D layout col=lane&15, row=(lane>>4)*4+reg  [m89/m91]
  const int colb = n0 + wn * 32;
#pragma unroll
  for (int fm = 0; fm < 4; ++fm) {
    int row0 = m0 + wm * 64 + fm * 16 + kg * 4;
#pragma unroll
    for (int fn = 0; fn < 2; ++fn) {
      int c = colb + fn * 16 + rl;
      float bv = bias[c];
#pragma unroll
      for (int rg = 0; rg < 4; ++rg) {
        int row = row0 + rg;
        if (row < M) {
          float rs = rowscale ? rowscale[row] : 1.0f;
          float v = acc[fm][fn][rg] + rs * bv;
          if (act) v = leaky(v);
          C[(size_t)row * 256 + c] = f2b(v);
        }
      }
    }
  }
#undef LOAD_TILE
#undef STORE_TILE
}

// ---------------- fp32 SIMT GEMM (decoder only: M=16) ----------------
#define BM 128
#define BN 64
#define BK 16
__global__ __launch_bounds__(256) void k_gemm(
    const float* __restrict__ A0, const float* __restrict__ W0,
    const float* __restrict__ A1, const float* __restrict__ W1,
    const float* __restrict__ bias, const float* __restrict__ rowscale,
    float* __restrict__ C, int M, int N, int K, int act)
{
  __shared__ float As[BK][BM + 4];
  __shared__ float Bs[BK][BN + 4];
  int tid = threadIdx.x;
  int tx = tid & 15;
  int ty = tid >> 4;
  int m0 = blockIdx.x * BM;
  int n0 = blockIdx.y * BN;

  float c[8][4];
#pragma unroll
  for (int i = 0; i < 8; ++i)
#pragma unroll
    for (int j = 0; j < 4; ++j) c[i][j] = 0.f;

  int la_m = tid >> 2;
  int la_k = (tid & 3) << 2;
  int lb_k = tid >> 4;
  int lb_n = (tid & 15) << 2;

  int am1 = m0 + la_m;
  int am2 = am1 + 64;
  int bn = n0 + lb_n;
  bool bok = (bn + 4) <= N;

  int npass = (A1 != nullptr) ? 2 : 1;
  for (int p = 0; p < npass; ++p) {
    const float* __restrict__ A = p ? A1 : A0;
    const float* __restrict__ W = p ? W1 : W0;
    for (int k0 = 0; k0 < K; k0 += BK) {
      float4 av1 = make_float4(0.f, 0.f, 0.f, 0.f), av2 = av1;
      if (am1 < M) av1 = *(const float4*)&A[(size_t)am1 * K + k0 + la_k];
      if (am2 < M) av2 = *(const float4*)&A[(size_t)am2 * K + k0 + la_k];
      float4 bv = make_float4(0.f, 0.f, 0.f, 0.f);
      if (bok) bv = *(const float4*)&W[(size_t)(k0 + lb_k) * N + bn];
      __syncthreads();
      As[la_k + 0][la_m] = av1.x;
      As[la_k + 1][la_m] = av1.y;
      As[la_k + 2][la_m] = av1.z;
      As[la_k + 3][la_m] = av1.w;
      As[la_k + 0][la_m + 64] = av2.x;
      As[la_k + 1][la_m + 64] = av2.y;
      As[la_k + 2][la_m + 64] = av2.z;
      As[la_k + 3][la_m + 64] = av2.w;
      *(float4*)&Bs[lb_k][lb_n] = bv;
      __syncthreads();
#pragma unroll
      for (int k = 0; k < BK; ++k) {
        float4 a0 = *(const float4*)&As[k][ty * 8];
        float4 a1 = *(const float4*)&As[k][ty * 8 + 4];
        float4 b  = *(const float4*)&Bs[k][tx * 4];
        float a[8] = {a0.x, a0.y, a0.z, a0.w, a1.x, a1.y, a1.z, a1.w};
        float bb[4] = {b.x, b.y, b.z, b.w};
#pragma unroll
        for (int i = 0; i < 8; ++i)
#pragma unroll
          for (int j = 0; j < 4; ++j) c[i][j] += a[i] * bb[j];
      }
    }
  }

  int colbase = n0 + (tx << 2);
  if ((colbase + 4) > N) return;
  float4 bb = *(const float4*)&bias[colbase];
#pragma unroll
  for (int i = 0; i < 8; ++i) {
    int row = m0 + ty * 8 + i;
    if (row >= M) break;
    float rsv = (rowscale != nullptr) ? rowscale[row] : 1.f;
    float4 v;
    v.x = c[i][0] + bb.x * rsv;
    v.y = c[i][1] + bb.y * rsv;
    v.z = c[i][2] + bb.z * rsv;
    v.w = c[i][3] + bb.w * rsv;
    if (act) { v.x = leaky(v.x); v.y = leaky(v.y); v.z = leaky(v.z); v.w = leaky(v.w); }
    *(float4*)&C[(size_t)row * N + colbase] = v;
  }
}

// ---------------- pooling ----------------
__global__ __launch_bounds__(256) void k_pool1(const ushort* __restrict__ h, const int* __restrict__ gstart,
                                               const int* __restrict__ gcnt, float* __restrict__ psum,
                                               float* __restrict__ pmax) {
  int g = blockIdx.x >> 4;
  int cch = blockIdx.x & 15;
  int t = threadIdx.x;
  int len = gcnt[g];
  int s0 = gstart[g];
  int chunk = (len + 15) >> 4;
  int i0 = s0 + cch * chunk;
  int i1 = min(i0 + chunk, s0 + len);
  float s = 0.f;
  float m = -3.402823466e+38f;
  for (int i = i0; i < i1; ++i) {
    float v = b2f(h[(size_t)i * HID + t]);
    s += v;
    m = fmaxf(m, v);
  }
  psum[(size_t)blockIdx.x * HID + t] = s;
  pmax[(size_t)blockIdx.x * HID + t] = m;
}

__global__ __launch_bounds__(256) void k_pool2(const float* __restrict__ psum, const float* __restrict__ pmax,
                                               const int* __restrict__ gcnt, float* __restrict__ pooled) {
  int g = blockIdx.x;
  int t = threadIdx.x;
  float s = 0.f, m = -3.402823466e+38f;
  for (int cch = 0; cch < 16; ++cch) {
    s += psum[(size_t)(g * 16 + cch) * HID + t];
    m = fmaxf(m, pmax[(size_t)(g * 16 + cch) * HID + t]);
  }
  float cf = (float)gcnt[g];
  pooled[g * 3 * HID + t] = s / fmaxf(cf, 1.f);
  pooled[g * 3 * HID + HID + t] = m;
  pooled[g * 3 * HID + 2 * HID + t] = s;
}

// ---------------- launch ----------------
extern "C" void kernel_launch(void* const* d_in, const int* in_sizes, int n_in,
                              void* d_out, int out_size, void* d_ws, size_t ws_size,
                              hipStream_t stream) {
  const float* x        = (const float*)d_in[0];
  const int*   ei       = (const int*)d_in[1];
  const int*   batch    = (const int*)d_in[2];
  const float* enc_Win  = (const float*)d_in[3];
  const float* enc_bin  = (const float*)d_in[4];
  const float* enc_Wh   = (const float*)d_in[5];
  const float* enc_bh   = (const float*)d_in[6];
  const float* enc_Wout = (const float*)d_in[7];
  const float* enc_bout = (const float*)d_in[8];
  const float* edge_W   = (const float*)d_in[9];
  const float* edge_b   = (const float*)d_in[10];
  const float* proc_Win = (const float*)d_in[11];
  const float* proc_bin = (const float*)d_in[12];
  const float* proc_Wh  = (const float*)d_in[13];
  const float* proc_bh  = (const float*)d_in[14];
  const float* proc_Wout= (const float*)d_in[15];
  const float* proc_bout= (const float*)d_in[16];
  const float* dec_Win  = (const float*)d_in[17];
  const float* dec_bin  = (const float*)d_in[18];
  const float* dec_Wh   = (const float*)d_in[19];
  const float* dec_bh   = (const float*)d_in[20];
  const float* dec_Wout = (const float*)d_in[21];
  const float* dec_bout = (const float*)d_in[22];

  const int n  = in_sizes[0] / 128;  // 20000
  const int ne = in_sizes[1] / 2;    // 160000
  const int H = HID;

  // workspace carve-up
  char* p = (char*)d_ws;
  auto alloc = [&](size_t bytes) -> char* {
    char* r = p;
    p += (bytes + 255) & ~(size_t)255;
    return r;
  };
  ushort* hb0   = (ushort*)alloc((size_t)n * H * 2);
  ushort* hb1   = (ushort*)alloc((size_t)n * H * 2);
  ushort* Sb    = (ushort*)alloc((size_t)n * H * 2);
  ushort* hdb   = (ushort*)alloc((size_t)n * H * 2);
  ushort* xb    = (ushort*)alloc((size_t)n * 128 * 2);
  ushort* w_enc_in  = (ushort*)alloc((size_t)256 * 128 * 2);
  ushort* w_enc_h0  = (ushort*)alloc((size_t)256 * 256 * 2);
  ushort* w_enc_h1  = (ushort*)alloc((size_t)256 * 256 * 2);
  ushort* w_enc_out = (ushort*)alloc((size_t)256 * 256 * 2);
  ushort* w_proc_in  = (ushort*)alloc((size_t)256 * 256 * 2);
  ushort* w_proc_h0  = (ushort*)alloc((size_t)256 * 256 * 2);
  ushort* w_proc_h1  = (ushort*)alloc((size_t)256 * 256 * 2);
  ushort* w_proc_out = (ushort*)alloc((size_t)256 * 256 * 2);
  ushort* w_edge     = (ushort*)alloc((size_t)256 * 512 * 2);
  float* degf   = (float*)alloc((size_t)n * 4);
  float* pooled = (float*)alloc((size_t)NGRAPH * 3 * H * 4);
  float* psum   = (float*)alloc((size_t)256 * H * 4);
  float* pmax   = (float*)alloc((size_t)256 * H * 4);
  float* db0    = (float*)alloc((size_t)NGRAPH * H * 4);
  float* db1    = (float*)alloc((size_t)NGRAPH * H * 4);
  int* cnt    = (int*)alloc((size_t)n * 4);
  int* rowptr = (int*)alloc((size_t)(n + 1) * 4);
  int* cursor = (int*)alloc((size_t)n * 4);
  int* gstart = (int*)alloc((size_t)(NGRAPH + 1) * 4);
  int* gcnt   = (int*)alloc((size_t)NGRAPH * 4);
  int* colv   = (int*)alloc((size_t)ne * 4);

  const int* srcI = ei;
  const int* dstI = ei + ne;

  dim3 blk(256);

  // weight conversions (transpose to [N=256][K] bf16)
  k_wconv<<<dim3(128 / 32, 8), blk, 0, stream>>>(enc_Win, w_enc_in, 128);
  k_wconv<<<dim3(256 / 32, 8), blk, 0, stream>>>(enc_Wh, w_enc_h0, 256);
  k_wconv<<<dim3(256 / 32, 8), blk, 0, stream>>>(enc_Wh + 256 * 256, w_enc_h1, 256);
  k_wconv<<<dim3(256 / 32, 8), blk, 0, stream>>>(enc_Wout, w_enc_out, 256);
  k_wconv<<<dim3(256 / 32, 8), blk, 0, stream>>>(proc_Win, w_proc_in, 256);
  k_wconv<<<dim3(256 / 32, 8), blk, 0, stream>>>(proc_Wh, w_proc_h0, 256);
  k_wconv<<<dim3(256 / 32, 8), blk, 0, stream>>>(proc_Wh + 256 * 256, w_proc_h1, 256);
  k_wconv<<<dim3(256 / 32, 8), blk, 0, stream>>>(proc_Wout, w_proc_out, 256);
  k_wconv<<<dim3(512 / 32, 8), blk, 0, stream>>>(edge_W, w_edge, 512);  // rows 512..767 hit e==0
  k_f2b<<<dim3((n * 128 / 4 + 255) / 256), blk, 0, stream>>>(x, xb, n * 128);

  // CSR by destination + per-graph bounds
  k_zero_i32<<<dim3((n + 255) / 256), blk, 0, stream>>>(cnt, n);
  k_hist<<<dim3((ne + 255) / 256), blk, 0, stream>>>(dstI, cnt, ne);
  k_scan<<<1, 1024, 0, stream>>>(cnt, rowptr, cursor, n);
  k_gbounds<<<1, 64, 0, stream>>>(batch, n, gstart, gcnt);
  k_scatter<<<dim3((ne + 255) / 256), blk, 0, stream>>>(srcI, dstI, cursor, colv, ne);

  dim3 gg((n + 127) / 128, 4);  // (157, 4)

  // encoder
  k_gemm_bf16<<<gg, blk, 0, stream>>>(xb,  w_enc_in, 128, nullptr, nullptr, 0, enc_bin,      nullptr, hb0, n, 128, 1);
  k_gemm_bf16<<<gg, blk, 0, stream>>>(hb0, w_enc_h0, 256, nullptr, nullptr, 0, enc_bh,       nullptr, hb1, n, 256, 1);
  k_gemm_bf16<<<gg, blk, 0, stream>>>(hb1, w_enc_h1, 256, nullptr, nullptr, 0, enc_bh + 256, nullptr, hb0, n, 256, 1);
  k_gemm_bf16<<<gg, blk, 0, stream>>>(hb0, w_enc_out, 256, nullptr, nullptr, 0, enc_bout,    nullptr, hb1, n, 256, 0);

  // 4 message-passing rounds; h in hb1 at loop head
  for (int r = 0; r < 4; ++r) {
    k_aggregate<<<dim3((n + 3) / 4), blk, 0, stream>>>(hb1, rowptr, colv, Sb, hdb, degf, n);
    // agg = (deg.*h)@W1 + S@W2 + deg.*edge_b
    k_gemm_bf16<<<gg, blk, 0, stream>>>(hdb, w_edge, 512, Sb, w_edge + 256, 512, edge_b, degf, hb0, n, 256, 0);
    // proc MLP
    k_gemm_bf16<<<gg, blk, 0, stream>>>(hb0, w_proc_in, 256, nullptr, nullptr, 0, proc_bin,       nullptr, Sb,  n, 256, 1);
    k_gemm_bf16<<<gg, blk, 0, stream>>>(Sb,  w_proc_h0, 256, nullptr, nullptr, 0, proc_bh,        nullptr, hb0, n, 256, 1);
    k_gemm_bf16<<<gg, blk, 0, stream>>>(hb0, w_proc_h1, 256, nullptr, nullptr, 0, proc_bh + 256,  nullptr, Sb,  n, 256, 1);
    k_gemm_bf16<<<gg, blk, 0, stream>>>(Sb,  w_proc_out, 256, nullptr, nullptr, 0, proc_bout,     nullptr, hb1, n, 256, 0);
  }

  // pooling
  k_pool1<<<dim3(NGRAPH * 16), blk, 0, stream>>>(hb1, gstart, gcnt, psum, pmax);
  k_pool2<<<dim3(NGRAPH), blk, 0, stream>>>(psum, pmax, gcnt, pooled);

  // decoder (fp32 SIMT; M=16 tiny)
  dim3 g_dec(1, 4);
  k_gemm<<<g_dec, blk, 0, stream>>>(pooled, dec_Win,        nullptr, nullptr, dec_bin,    nullptr, db0, NGRAPH, 256, 3 * H, 1);
  k_gemm<<<g_dec, blk, 0, stream>>>(db0,    dec_Wh,         nullptr, nullptr, dec_bh,     nullptr, db1, NGRAPH, 256, 256, 1);
  k_gemm<<<g_dec, blk, 0, stream>>>(db1,    dec_Wh + 256 * 256, nullptr, nullptr, dec_bh + 256, nullptr, db0, NGRAPH, 256, 256, 1);
  k_gemm<<<dim3(1, 1), blk, 0, stream>>>(db0, dec_Wout,     nullptr, nullptr, dec_bout,   nullptr, (float*)d_out, NGRAPH, 32, 256, 0);
}